// Round 3
// baseline (41.807 us; speedup 1.0000x reference)
//
#include <hip/hip_runtime.h>
#include <hip/hip_bf16.h>

#define B_SZ 4096
#define F_N  39
#define V_N  100000
#define D_N  16
#define H_N  400
#define K1   624      // F*D
#define K1P  640      // K1 padded to mult of 64
#define NP   512      // H padded to mult of 64

typedef __attribute__((ext_vector_type(8))) short short8;
typedef __attribute__((ext_vector_type(4))) float f32x4;

typedef const __attribute__((address_space(1))) void g_void;
typedef __attribute__((address_space(3))) void l_void;

// -------------------- kernel 1: gather + fst + FM + bf16 sec_flat ------------
// 256 threads / block, one batch row per block. float4 gathers (4 lanes/row).
__global__ __launch_bounds__(256) void gather_kernel(
    const int*   __restrict__ Xi,
    const float* __restrict__ Xv,
    const float* __restrict__ fst_t,
    const float* __restrict__ sec_t,
    const float* __restrict__ bias,
    __hip_bfloat16* __restrict__ sec_flat,
    float* __restrict__ out)
{
    const int b   = blockIdx.x;
    const int tid = threadIdx.x;

    __shared__ float smem[K1];     // sec values (fp32) for FM column sums
    __shared__ float red[4];       // per-wave sumsq partials
    __shared__ int   sidx[F_N];
    __shared__ float sval[F_N];

    if (tid < F_N) {
        sidx[tid] = Xi[b * F_N + tid];
        sval[tid] = Xv[b * F_N + tid];
    }
    __syncthreads();

    // lanes 0..155: each handles 4 contiguous elems of one sec row (16B load)
    float4 v4 = make_float4(0.f, 0.f, 0.f, 0.f);
    float sumsq = 0.f;
    if (tid < 156) {
        const int f = tid >> 2;
        const int q = tid & 3;
        const float4 r = *(const float4*)(sec_t + ((long long)f * V_N + sidx[f]) * D_N + q * 4);
        const float val = sval[f];
        v4.x = r.x * val; v4.y = r.y * val; v4.z = r.z * val; v4.w = r.w * val;
        smem[tid * 4 + 0] = v4.x;
        smem[tid * 4 + 1] = v4.y;
        smem[tid * 4 + 2] = v4.z;
        smem[tid * 4 + 3] = v4.w;
        sumsq = v4.x * v4.x + v4.y * v4.y + v4.z * v4.z + v4.w * v4.w;
    }
    // bf16 store, 8B/lane; lanes 156..159 zero-fill the 624..639 pad
    if (tid < 160) {
        ushort4 p;
        p.x = __bfloat16_as_ushort(__float2bfloat16(v4.x));
        p.y = __bfloat16_as_ushort(__float2bfloat16(v4.y));
        p.z = __bfloat16_as_ushort(__float2bfloat16(v4.z));
        p.w = __bfloat16_as_ushort(__float2bfloat16(v4.w));
        *(ushort4*)(sec_flat + (size_t)b * K1P + tid * 4) = p;
    }

    // wave-reduce sumsq
    for (int off = 32; off; off >>= 1) sumsq += __shfl_down(sumsq, off, 64);
    if ((tid & 63) == 0) red[tid >> 6] = sumsq;
    __syncthreads();

    if (tid < 64) {
        float fs = 0.f;
        if (tid < F_N)
            fs = fst_t[(long long)tid * V_N + sidx[tid]] * sval[tid];
        float fm = 0.f;
        if (tid < D_N) {
            float s = 0.f;
            #pragma unroll
            for (int f = 0; f < F_N; ++f) s += smem[f * D_N + tid];
            fm = 0.5f * s * s;
        }
        float t = fs + fm;
        for (int off = 32; off; off >>= 1) t += __shfl_down(t, off, 64);
        if (tid == 0)
            out[b] = t - 0.5f * (red[0] + red[1] + red[2] + red[3]) + bias[0];
    }
}

// ------------- kernel 2: weight transpose+pad+bf16 convert -------------------
#define CVT_W1  (NP * K1P)
#define CVT_W2  (NP * NP)
#define CVT_TOT (CVT_W1 + CVT_W2 + NP + NP)
__global__ __launch_bounds__(256) void convert_kernel(
    const float* __restrict__ W1, const float* __restrict__ b1,
    const float* __restrict__ W2, const float* __restrict__ b2,
    __hip_bfloat16* __restrict__ W1t, __hip_bfloat16* __restrict__ W2t,
    float* __restrict__ b1p, float* __restrict__ b2p)
{
    int i = blockIdx.x * 256 + threadIdx.x;
    if (i < CVT_W1) {
        const int n = i / K1P, k = i % K1P;
        W1t[i] = __float2bfloat16((n < H_N && k < K1) ? W1[k * H_N + n] : 0.f);
        return;
    }
    i -= CVT_W1;
    if (i < CVT_W2) {
        const int n = i / NP, k = i % NP;
        W2t[i] = __float2bfloat16((n < H_N && k < H_N) ? W2[k * H_N + n] : 0.f);
        return;
    }
    i -= CVT_W2;
    if (i < NP) { b1p[i] = (i < H_N) ? b1[i] : 0.f; return; }
    i -= NP;
    if (i < NP) { b2p[i] = (i < H_N) ? b2[i] : 0.f; }
}

// ------------- kernel 3/4: bf16 MFMA GEMM, 64x64 tile, BK=64, 2-phase --------
// C = relu(A @ Bt^T + bias)   (A: [M][KT] bf16, Bt: [NP][KT] bf16 = W^T)
// ROWSUM: atomicAdd per-row sums of relu(...) into out instead of storing C
template <int KT, bool ROWSUM>
__global__ __launch_bounds__(256) void mfma_gemm(
    const __hip_bfloat16* __restrict__ A,
    const __hip_bfloat16* __restrict__ Bt,
    const float* __restrict__ bias,
    __hip_bfloat16* __restrict__ C,
    float* __restrict__ out)
{
    __shared__ __align__(16) __hip_bfloat16 As[2][64 * 64];
    __shared__ __align__(16) __hip_bfloat16 Bs[2][64 * 64];

    const int tid  = threadIdx.x;
    const int lane = tid & 63;
    const int wid  = tid >> 6;           // 4 waves: 2 (M) x 2 (N)
    const int wm   = wid >> 1;
    const int wn   = wid & 1;
    const int row0 = blockIdx.y * 64;
    const int col0 = blockIdx.x * 64;
    const int lr   = lane & 15;          // frag row/col
    const int lk   = (lane >> 4) * 8;    // frag k-offset

    f32x4 acc[2][2] = {};

    const int sr = tid >> 3;             // staging row 0..31
    const int sc = (tid & 7) * 8;        // staging col chunk (8 bf16 = 16 B)

    // per-lane LDS dest is linear in tid (tid*16B) -> gload_lds constraint OK
    auto STAGE = [&](int buf, int k0) {
        #pragma unroll
        for (int i = 0; i < 2; ++i) {
            __builtin_amdgcn_global_load_lds(
                (g_void*)(A + (size_t)(row0 + i * 32 + sr) * KT + k0 + sc),
                (l_void*)(&As[buf][(i * 32 + sr) * 64 + sc]), 16, 0, 0);
            __builtin_amdgcn_global_load_lds(
                (g_void*)(Bt + (size_t)(col0 + i * 32 + sr) * KT + k0 + sc),
                (l_void*)(&Bs[buf][(i * 32 + sr) * 64 + sc]), 16, 0, 0);
        }
    };

    constexpr int NT = KT / 64;
    STAGE(0, 0);
    __syncthreads();                     // drains vmcnt(0): buf0 ready

    int cur = 0;
    for (int t = 0; t < NT; ++t) {
        if (t + 1 < NT) STAGE(cur ^ 1, (t + 1) * 64);   // issue next-tile loads FIRST
        #pragma unroll
        for (int ks = 0; ks < 2; ++ks) {
            short8 a[2], bb[2];
            #pragma unroll
            for (int m = 0; m < 2; ++m)
                a[m] = *(const short8*)(&As[cur][(wm * 32 + m * 16 + lr) * 64 + ks * 32 + lk]);
            #pragma unroll
            for (int n = 0; n < 2; ++n)
                bb[n] = *(const short8*)(&Bs[cur][(wn * 32 + n * 16 + lr) * 64 + ks * 32 + lk]);
            #pragma unroll
            for (int m = 0; m < 2; ++m)
                #pragma unroll
                for (int n = 0; n < 2; ++n)
                    acc[m][n] = __builtin_amdgcn_mfma_f32_16x16x32_bf16(
                        a[m], bb[n], acc[m][n], 0, 0, 0);
        }
        if (t + 1 < NT) {
            __syncthreads();             // drains vmcnt(0)+lgkmcnt(0): next buf ready
            cur ^= 1;
        }
    }

    // epilogue — C/D layout: col = lane&15, row = (lane>>4)*4 + reg  [m89]
    if constexpr (!ROWSUM) {
        #pragma unroll
        for (int m = 0; m < 2; ++m) {
            const int row = row0 + wm * 32 + m * 16 + (lane >> 4) * 4;
            #pragma unroll
            for (int n = 0; n < 2; ++n) {
                const int col = col0 + wn * 32 + n * 16 + lr;
                const float bv = bias[col];
                #pragma unroll
                for (int r = 0; r < 4; ++r)
                    C[(size_t)(row + r) * NP + col] =
                        __float2bfloat16(fmaxf(acc[m][n][r] + bv, 0.f));
            }
        }
    } else {
        #pragma unroll
        for (int m = 0; m < 2; ++m) {
            float v[4] = {0.f, 0.f, 0.f, 0.f};
            #pragma unroll
            for (int n = 0; n < 2; ++n) {
                const int col = col0 + wn * 32 + n * 16 + lr;
                const float bv = bias[col];
                #pragma unroll
                for (int r = 0; r < 4; ++r)
                    v[r] += fmaxf(acc[m][n][r] + bv, 0.f);
            }
            // reduce across the 16 cols (xor 1,2,4,8 within 16-lane groups)
            #pragma unroll
            for (int off = 1; off < 16; off <<= 1)
                #pragma unroll
                for (int r = 0; r < 4; ++r)
                    v[r] += __shfl_xor(v[r], off, 64);
            if (lr == 0) {
                const int row = row0 + wm * 32 + m * 16 + (lane >> 4) * 4;
                #pragma unroll
                for (int r = 0; r < 4; ++r)
                    atomicAdd(out + row + r, v[r]);
            }
        }
    }
}

extern "C" void kernel_launch(void* const* d_in, const int* in_sizes, int n_in,
                              void* d_out, int out_size, void* d_ws, size_t ws_size,
                              hipStream_t stream)
{
    const int*   Xi    = (const int*)  d_in[0];
    const float* Xv    = (const float*)d_in[1];
    const float* fst_t = (const float*)d_in[2];
    const float* sec_t = (const float*)d_in[3];
    const float* W1    = (const float*)d_in[4];
    const float* b1    = (const float*)d_in[5];
    const float* W2    = (const float*)d_in[6];
    const float* b2    = (const float*)d_in[7];
    const float* bias  = (const float*)d_in[8];

    float* out = (float*)d_out;
    char*  wsb = (char*)d_ws;

    // ws layout (bytes)
    __hip_bfloat16* sec_flat = (__hip_bfloat16*)(wsb);                 // 4096*640*2
    __hip_bfloat16* h        = (__hip_bfloat16*)(wsb + 5242880);       // 4096*512*2
    __hip_bfloat16* W1t      = (__hip_bfloat16*)(wsb + 9437184);       // 512*640*2
    __hip_bfloat16* W2t      = (__hip_bfloat16*)(wsb + 10092544);      // 512*512*2
    float*          b1p      = (float*)(wsb + 10616832);               // 512*4
    float*          b2p      = (float*)(wsb + 10618880);               // 512*4

    convert_kernel<<<(CVT_TOT + 255) / 256, 256, 0, stream>>>(W1, b1, W2, b2, W1t, W2t, b1p, b2p);
    gather_kernel<<<B_SZ, 256, 0, stream>>>(Xi, Xv, fst_t, sec_t, bias, sec_flat, out);

    dim3 grid(NP / 64, B_SZ / 64);   // (8, 64) = 512 blocks
    mfma_gemm<K1P, false><<<grid, 256, 0, stream>>>(sec_flat, W1t, b1p, h, nullptr);
    mfma_gemm<NP,  true ><<<grid, 256, 0, stream>>>(h, W2t, b2p, nullptr, out);
}

// Round 4
// 41.345 us; speedup vs baseline: 1.0112x; 1.0112x over previous
//
#include <hip/hip_runtime.h>
#include <hip/hip_bf16.h>

#define B_SZ 4096
#define F_N  39
#define V_N  100000
#define D_N  16
#define H_N  400
#define K1   624      // F*D
#define K1P  640      // K1 padded to mult of 64
#define NP   512      // H padded to mult of 64

typedef __attribute__((ext_vector_type(8))) short short8;
typedef __attribute__((ext_vector_type(4))) float f32x4;

typedef const __attribute__((address_space(1))) void g_void;
typedef __attribute__((address_space(3))) void l_void;

#define W1_TILES (10 * 8)            // K1P/64 x NP/64
#define W2_TILES (8 * 8)             // 512/64 x 512/64
#define PREP_GRID (B_SZ + W1_TILES + W2_TILES + 1)

// ---- kernel 1: gather + fst + FM + bf16 sec_flat, FUSED with weight prep ----
__global__ __launch_bounds__(256) void prep_kernel(
    const int*   __restrict__ Xi,
    const float* __restrict__ Xv,
    const float* __restrict__ fst_t,
    const float* __restrict__ sec_t,
    const float* __restrict__ bias,
    const float* __restrict__ W1, const float* __restrict__ b1,
    const float* __restrict__ W2, const float* __restrict__ b2,
    __hip_bfloat16* __restrict__ sec_flat,
    __hip_bfloat16* __restrict__ W1t, __hip_bfloat16* __restrict__ W2t,
    float* __restrict__ b1p, float* __restrict__ b2p,
    float* __restrict__ out)
{
    const int bid = blockIdx.x;
    const int tid = threadIdx.x;

    __shared__ float tile[64][65];     // transpose staging (union-sized LDS)
    __shared__ float smem[K1];
    __shared__ float red[4];
    __shared__ int   sidx[F_N];
    __shared__ float sval[F_N];

    if (bid < B_SZ) {
        // -------------------- gather branch --------------------
        const int b = bid;
        if (tid < F_N) {
            sidx[tid] = Xi[b * F_N + tid];
            sval[tid] = Xv[b * F_N + tid];
        }
        __syncthreads();

        float4 v4 = make_float4(0.f, 0.f, 0.f, 0.f);
        float sumsq = 0.f;
        if (tid < 156) {
            const int f = tid >> 2;
            const int q = tid & 3;
            const float4 r = *(const float4*)(sec_t + ((long long)f * V_N + sidx[f]) * D_N + q * 4);
            const float val = sval[f];
            v4.x = r.x * val; v4.y = r.y * val; v4.z = r.z * val; v4.w = r.w * val;
            smem[tid * 4 + 0] = v4.x;
            smem[tid * 4 + 1] = v4.y;
            smem[tid * 4 + 2] = v4.z;
            smem[tid * 4 + 3] = v4.w;
            sumsq = v4.x * v4.x + v4.y * v4.y + v4.z * v4.z + v4.w * v4.w;
        }
        if (tid < 160) {
            ushort4 p;
            p.x = __bfloat16_as_ushort(__float2bfloat16(v4.x));
            p.y = __bfloat16_as_ushort(__float2bfloat16(v4.y));
            p.z = __bfloat16_as_ushort(__float2bfloat16(v4.z));
            p.w = __bfloat16_as_ushort(__float2bfloat16(v4.w));
            *(ushort4*)(sec_flat + (size_t)b * K1P + tid * 4) = p;
        }

        for (int off = 32; off; off >>= 1) sumsq += __shfl_down(sumsq, off, 64);
        if ((tid & 63) == 0) red[tid >> 6] = sumsq;
        __syncthreads();

        if (tid < 64) {
            float fs = 0.f;
            if (tid < F_N)
                fs = fst_t[(long long)tid * V_N + sidx[tid]] * sval[tid];
            float fm = 0.f;
            if (tid < D_N) {
                float s = 0.f;
                #pragma unroll
                for (int f = 0; f < F_N; ++f) s += smem[f * D_N + tid];
                fm = 0.5f * s * s;
            }
            float t = fs + fm;
            for (int off = 32; off; off >>= 1) t += __shfl_down(t, off, 64);
            if (tid == 0)
                out[b] = t - 0.5f * (red[0] + red[1] + red[2] + red[3]) + bias[0];
        }
        return;
    }

    int tb = bid - B_SZ;
    if (tb < W1_TILES + W2_TILES) {
        // -------------------- weight transpose branch --------------------
        // src W [Ksrc][H_N] fp32 -> dst Wt [NP][Kdst] bf16 (zero-padded)
        const float* Wsrc;
        __hip_bfloat16* Wdst;
        int Ksrc, Kdst, kb, nb;
        if (tb < W1_TILES) { Wsrc = W1; Wdst = W1t; Ksrc = K1;  Kdst = K1P; kb = tb / 8; nb = tb % 8; }
        else { tb -= W1_TILES; Wsrc = W2; Wdst = W2t; Ksrc = H_N; Kdst = NP;  kb = tb / 8; nb = tb % 8; }
        const int k0 = kb * 64, n0 = nb * 64;

        #pragma unroll
        for (int p = 0; p < 4; ++p) {
            const int r  = (tid >> 4) + p * 16;     // src row offset (k)
            const int c4 = (tid & 15) * 4;          // src col offset (n)
            const int gk = k0 + r, gn = n0 + c4;
            float4 v = make_float4(0.f, 0.f, 0.f, 0.f);
            if (gk < Ksrc && gn + 3 < H_N)
                v = *(const float4*)(Wsrc + (size_t)gk * H_N + gn);
            tile[c4 + 0][r] = v.x;
            tile[c4 + 1][r] = v.y;
            tile[c4 + 2][r] = v.z;
            tile[c4 + 3][r] = v.w;
        }
        __syncthreads();
        const int rr = tid >> 2;            // dst row offset (n)
        const int cc = (tid & 3) * 16;      // dst col offset (k)
        short8 s0, s1;
        #pragma unroll
        for (int j = 0; j < 8; ++j) {
            s0[j] = (short)__bfloat16_as_ushort(__float2bfloat16(tile[rr][cc + j]));
            s1[j] = (short)__bfloat16_as_ushort(__float2bfloat16(tile[rr][cc + 8 + j]));
        }
        *(short8*)(Wdst + (size_t)(n0 + rr) * Kdst + k0 + cc)     = s0;
        *(short8*)(Wdst + (size_t)(n0 + rr) * Kdst + k0 + cc + 8) = s1;
        return;
    }

    // -------------------- bias pad branch (1 block) --------------------
    if (tid < 256) {
        b1p[tid]       = (tid < H_N)       ? b1[tid]       : 0.f;
        b1p[tid + 256] = (tid + 256 < H_N) ? b1[tid + 256] : 0.f;
        b2p[tid]       = (tid < H_N)       ? b2[tid]       : 0.f;
        b2p[tid + 256] = (tid + 256 < H_N) ? b2[tid + 256] : 0.f;
    }
}

// ------- kernel 2/3: bf16 MFMA GEMM, 64x64 tile, BK=128, 2-phase, XCD-swz ----
// C = relu(A @ Bt^T + bias)   (A: [M][KT] bf16, Bt: [NP][KT] bf16 = W^T)
// ROWSUM: atomicAdd per-row sums of relu(...) into out instead of storing C
template <int KT, bool ROWSUM>
__global__ __launch_bounds__(256) void mfma_gemm(
    const __hip_bfloat16* __restrict__ A,
    const __hip_bfloat16* __restrict__ Bt,
    const float* __restrict__ bias,
    __hip_bfloat16* __restrict__ C,
    float* __restrict__ out)
{
    __shared__ __align__(16) __hip_bfloat16 As[2][64 * 128];
    __shared__ __align__(16) __hip_bfloat16 Bs[2][64 * 128];

    const int tid  = threadIdx.x;
    const int lane = tid & 63;
    const int wid  = tid >> 6;           // 4 waves: 2 (M) x 2 (N)
    const int wm   = wid >> 1;
    const int wn   = wid & 1;

    // XCD-chunked swizzle: 512 blocks, 8 XCDs, 64 consecutive tiles per XCD.
    // XCD k gets row-panels 8k..8k+7 (all col tiles) -> A-panel L2 locality.
    const int lin  = blockIdx.x;
    const int nb   = (lin & 7) * 64 + (lin >> 3);
    const int row0 = (nb >> 3) * 64;
    const int col0 = (nb & 7) * 64;

    const int lr = lane & 15;            // frag row/col
    const int lk = (lane >> 4) * 8;      // frag k-offset

    f32x4 acc[2][2] = {};

    const int sr = tid >> 4;             // staging row 0..15 (+16/round)
    const int sc = (tid & 15) * 8;       // staging col chunk (8 bf16 = 16 B)

    // LDS dest elem = (sr+i*16)*128 + sc = wave_base + lane*8 elems -> linear OK
    auto STAGE = [&](int buf, int k0) {
        #pragma unroll
        for (int i = 0; i < 4; ++i) {
            __builtin_amdgcn_global_load_lds(
                (g_void*)(A + (size_t)(row0 + sr + i * 16) * KT + k0 + sc),
                (l_void*)(&As[buf][(sr + i * 16) * 128 + sc]), 16, 0, 0);
            __builtin_amdgcn_global_load_lds(
                (g_void*)(Bt + (size_t)(col0 + sr + i * 16) * KT + k0 + sc),
                (l_void*)(&Bs[buf][(sr + i * 16) * 128 + sc]), 16, 0, 0);
        }
    };

    constexpr int NT = KT / 128;
    STAGE(0, 0);
    __syncthreads();

    int cur = 0;
    for (int t = 0; t < NT; ++t) {
        if (t + 1 < NT) STAGE(cur ^ 1, (t + 1) * 128);   // issue next-tile loads FIRST
        #pragma unroll
        for (int kk = 0; kk < 4; ++kk) {
            short8 a[2], bb[2];
            #pragma unroll
            for (int m = 0; m < 2; ++m)
                a[m] = *(const short8*)(&As[cur][(wm * 32 + m * 16 + lr) * 128 + kk * 32 + lk]);
            #pragma unroll
            for (int n = 0; n < 2; ++n)
                bb[n] = *(const short8*)(&Bs[cur][(wn * 32 + n * 16 + lr) * 128 + kk * 32 + lk]);
            #pragma unroll
            for (int m = 0; m < 2; ++m)
                #pragma unroll
                for (int n = 0; n < 2; ++n)
                    acc[m][n] = __builtin_amdgcn_mfma_f32_16x16x32_bf16(
                        a[m], bb[n], acc[m][n], 0, 0, 0);
        }
        if (t + 1 < NT) {
            __syncthreads();
            cur ^= 1;
        }
    }

    // epilogue — C/D layout: col = lane&15, row = (lane>>4)*4 + reg  [m89]
    if constexpr (!ROWSUM) {
        __syncthreads();                          // done reading As/Bs
        float* ctile = (float*)&As[0][0];         // 64x64 fp32 = 16 KB
        #pragma unroll
        for (int m = 0; m < 2; ++m) {
            const int rbase = wm * 32 + m * 16 + (lane >> 4) * 4;
            #pragma unroll
            for (int n = 0; n < 2; ++n) {
                const int col = wn * 32 + n * 16 + lr;
                const float bv = bias[col0 + col];
                #pragma unroll
                for (int r = 0; r < 4; ++r)
                    ctile[(rbase + r) * 64 + col] = fmaxf(acc[m][n][r] + bv, 0.f);
            }
        }
        __syncthreads();
        const int row = tid >> 2;
        const int cc  = (tid & 3) * 16;
        short8 s0, s1;
        #pragma unroll
        for (int j = 0; j < 8; ++j) {
            s0[j] = (short)__bfloat16_as_ushort(__float2bfloat16(ctile[row * 64 + cc + j]));
            s1[j] = (short)__bfloat16_as_ushort(__float2bfloat16(ctile[row * 64 + cc + 8 + j]));
        }
        *(short8*)(C + (size_t)(row0 + row) * NP + col0 + cc)     = s0;
        *(short8*)(C + (size_t)(row0 + row) * NP + col0 + cc + 8) = s1;
    } else {
        #pragma unroll
        for (int m = 0; m < 2; ++m) {
            float v[4] = {0.f, 0.f, 0.f, 0.f};
            #pragma unroll
            for (int n = 0; n < 2; ++n) {
                const int col = col0 + wn * 32 + n * 16 + lr;
                const float bv = bias[col];
                #pragma unroll
                for (int r = 0; r < 4; ++r)
                    v[r] += fmaxf(acc[m][n][r] + bv, 0.f);
            }
            #pragma unroll
            for (int off = 1; off < 16; off <<= 1)
                #pragma unroll
                for (int r = 0; r < 4; ++r)
                    v[r] += __shfl_xor(v[r], off, 64);
            if (lr == 0) {
                const int row = row0 + wm * 32 + m * 16 + (lane >> 4) * 4;
                #pragma unroll
                for (int r = 0; r < 4; ++r)
                    atomicAdd(out + row + r, v[r]);
            }
        }
    }
}

extern "C" void kernel_launch(void* const* d_in, const int* in_sizes, int n_in,
                              void* d_out, int out_size, void* d_ws, size_t ws_size,
                              hipStream_t stream)
{
    const int*   Xi    = (const int*)  d_in[0];
    const float* Xv    = (const float*)d_in[1];
    const float* fst_t = (const float*)d_in[2];
    const float* sec_t = (const float*)d_in[3];
    const float* W1    = (const float*)d_in[4];
    const float* b1    = (const float*)d_in[5];
    const float* W2    = (const float*)d_in[6];
    const float* b2    = (const float*)d_in[7];
    const float* bias  = (const float*)d_in[8];

    float* out = (float*)d_out;
    char*  wsb = (char*)d_ws;

    __hip_bfloat16* sec_flat = (__hip_bfloat16*)(wsb);                 // 4096*640*2
    __hip_bfloat16* h        = (__hip_bfloat16*)(wsb + 5242880);       // 4096*512*2
    __hip_bfloat16* W1t      = (__hip_bfloat16*)(wsb + 9437184);       // 512*640*2
    __hip_bfloat16* W2t      = (__hip_bfloat16*)(wsb + 10092544);      // 512*512*2
    float*          b1p      = (float*)(wsb + 10616832);               // 512*4
    float*          b2p      = (float*)(wsb + 10618880);               // 512*4

    prep_kernel<<<PREP_GRID, 256, 0, stream>>>(
        Xi, Xv, fst_t, sec_t, bias, W1, b1, W2, b2,
        sec_flat, W1t, W2t, b1p, b2p, out);

    mfma_gemm<K1P, false><<<512, 256, 0, stream>>>(sec_flat, W1t, b1p, h, nullptr);
    mfma_gemm<NP,  true ><<<512, 256, 0, stream>>>(h, W2t, b2p, nullptr, out);
}